// Round 11
// baseline (1747.321 us; speedup 1.0000x reference)
//
#include <hip/hip_runtime.h>

#define NB 64
#define NC 32
#define NH 16
#define NW 16
#define NE 4096
#define NTOT (NB*NC*NH*NW)   // 524288
#define IDXW 341             // 1+4+16+64+256
#define GRID 256
#define TPB 1024

typedef float f32x2 __attribute__((ext_vector_type(2)));
typedef float f32x4 __attribute__((ext_vector_type(4)));

__device__ __forceinline__ f32x2 pkfma(f32x2 a, f32x2 b, f32x2 c) {
#if __has_builtin(__builtin_elementwise_fma)
  return __builtin_elementwise_fma(a, b, c);
#else
  return (f32x2){fmaf(a.x, b.x, c.x), fmaf(a.y, b.y, c.y)};
#endif
}

__device__ __forceinline__ double cubicw(double x) {
  const double A = -0.75;
  x = fabs(x);
  if (x <= 1.0) return ((A + 2.0) * x - (A + 3.0)) * x * x + 1.0;
  if (x < 2.0)  return A * (((x - 5.0) * x + 8.0) * x - 4.0);
  return 0.0;
}

// monotonic u32 key: smaller float <=> smaller key (handles negatives)
__device__ __forceinline__ unsigned monokey(float f) {
  unsigned u = __float_as_uint(f);
  return (u & 0x80000000u) ? ~u : (u | 0x80000000u);
}

__device__ __forceinline__ unsigned aload(unsigned* p) {
  return __hip_atomic_load(p, __ATOMIC_RELAXED, __HIP_MEMORY_SCOPE_AGENT);
}

// 4-party group barrier, fence-free (proven R2-R10): sc0sc1 publishes are
// coherent at IF$; __syncthreads drains vmcnt before arrive.
__device__ __forceinline__ void groupbar(unsigned* fl) {
  __syncthreads();
  if (threadIdx.x == 0) {
    __hip_atomic_fetch_add(fl, 1u, __ATOMIC_RELAXED, __HIP_MEMORY_SCOPE_AGENT);
    while (aload(fl) < 4u) __builtin_amdgcn_s_sleep(1);
  }
  __syncthreads();
}

// LDS byte map (64 KB), collision-checked (R6 lesson: fidx must be OUTSIDE
// the simg halo region):
//   zres   [    0,16384)  persistent f64 [8][256]
//   pool:  pp [16384,24576), pooled [24576,28672)
//   scan:  rvt32 [16384,24576) rvt64 [24576,40960) wdu [40960,43008)
//          cand [43008,43264)
//   upsample/phi: simg [16384,57856) = [32][18][18] f32 halo image
//          tt [57856,61952) qs [61952,64000) wtab [64000,64256)
//          itab [64256,64320) fidx [64320,64832) red [64832,64960)
//
// R7-R10 lessons baked in: compiler pins 64 VGPR and SPILLS bigger scans
// (R7/R8: 3.9GB scratch traffic); scan kept at R5's proven liveness
// (acc f32x4[4] = 16 regs). Scan restructures (R9/R10) regressed: the
// emb_ti L2 stream is NOT the stall -- R5's scan is kept verbatim.
__global__ __launch_bounds__(TPB)
__attribute__((amdgpu_waves_per_eu(4, 4)))
void k_fused(
    const float* __restrict__ z, const float* __restrict__ emb,
    const float* __restrict__ phi_w, const float* __restrict__ phi_b,
    double* __restrict__ rv64, double* __restrict__ emb_sq,
    double* __restrict__ loss_d, float* __restrict__ emb_ti,
    float* __restrict__ emb_sq32, int* __restrict__ win,
    unsigned* __restrict__ cnt, unsigned* __restrict__ gbar,
    unsigned* __restrict__ flags,
    float* __restrict__ out_zhat, float* __restrict__ out_loss,
    float* __restrict__ out_idx)
{
  __shared__ double lds[8192];                 // 64 KB
  char* base = (char*)lds;
  double* zres = lds;                          // [8][256] f64, persistent
  char* qreg   = base + 16384;

  const int tid = threadIdx.x;
  // group = {b, b+64, b+128, b+192}: all == b (mod 8) -> same XCD under the
  // default bid%8 XCD round-robin -> exchange stays XCD-local.
  const int b = blockIdx.x & 63, jq = blockIdx.x >> 6;
  const int co0 = jq * 8;

  // idempotent CAS-init of poisoned (0xAA) sync cells
  if (tid < 16) atomicCAS(&flags[(b << 4) + tid], 0xAAAAAAAAu, 0u);
  if (tid == 0) {
    atomicCAS((unsigned long long*)loss_d, 0xAAAAAAAAAAAAAAAAull, 0ull);
    atomicCAS(cnt, 0xAAAAAAAAu, 0u);
    atomicCAS(gbar, 0xAAAAAAAAu, 0u);
  }

  // ---------- setup: zres <- z slice; emb_ti (k-pair interleave) + emb_sq ---
  #pragma unroll
  for (int t = 0; t < 2; t++) {
    int i = t * TPB + tid;
    zres[i] = (double)z[((b * NC + co0) << 8) + i];
  }
  {
    int c0 = blockIdx.x * 16;                  // 16 codes per block
    if (tid < 512) {
      int cl = tid >> 5, k = tid & 31;
      // layout: emb_ti[k2*8192 + code*2 + (k&1)]
      emb_ti[(k >> 1) * 8192 + (c0 + cl) * 2 + (k & 1)] = emb[(c0 + cl) * NC + k];
    }
    if (tid < 16) {
      const float* er = emb + (c0 + tid) * NC;
      double s = 0.0;
      #pragma unroll
      for (int j = 0; j < 8; j++)
        s += (double)er[4*j]*er[4*j] + (double)er[4*j+1]*er[4*j+1]
           + (double)er[4*j+2]*er[4*j+2] + (double)er[4*j+3]*er[4*j+3];
      emb_sq[c0 + tid] = s;
      emb_sq32[c0 + tid] = (float)s;
    }
  }
  // one-time FENCED tree barrier (only threadfence pair in the kernel):
  // publishes emb_ti/emb_sq/emb_sq32 for normal L2-cached reads thereafter.
  __syncthreads();
  if (tid == 0) {
    __threadfence();                           // release (wb L2)
    __hip_atomic_fetch_add(&flags[(b << 4) + 15], 1u, __ATOMIC_RELAXED,
                           __HIP_MEMORY_SCOPE_AGENT);
    if (jq == 0) {
      while (aload(&flags[(b << 4) + 15]) < 4u) __builtin_amdgcn_s_sleep(1);
      __hip_atomic_fetch_add(gbar, 1u, __ATOMIC_RELAXED,
                             __HIP_MEMORY_SCOPE_AGENT);
      while (aload(gbar) < 64u) __builtin_amdgcn_s_sleep(4);
      __hip_atomic_store(&flags[(b << 4) + 14], 1u, __ATOMIC_RELAXED,
                         __HIP_MEMORY_SCOPE_AGENT);
    } else {
      while (aload(&flags[(b << 4) + 14]) < 1u) __builtin_amdgcn_s_sleep(1);
    }
    __threadfence();                           // acquire (inv L2)
  }
  __syncthreads();

  double bloss = 0.0;
  // ticks = np.linspace(1/12, 11/12, 4) f64: si=2 tie breaks to pi=2
  const int pis[5]  = {0, 1, 2, 2, 3};
  const int offs[5] = {0, 1, 5, 21, 85};

  for (int si = 0; si < 5; si++) {
    const int ph = 1 << si, f = NH / ph, ph2 = ph * ph;
    const int idx_off = offs[si];

    // ---------- pool own 8 channels (f64) -> publish rv64 [b][n][c] ---------
    if (si == 4) {
      #pragma unroll
      for (int t = 0; t < 2; t++) {
        int i = t * TPB + tid;
        int pix = i >> 3, cc = i & 7;          // coalesced publish
        __hip_atomic_store(&rv64[(((b << 8) + pix) << 5) + co0 + cc],
                           zres[cc * 256 + pix],
                           __ATOMIC_RELAXED, __HIP_MEMORY_SCOPE_AGENT);
      }
    } else {
      double* pp = (double*)qreg;              // partials  [16K,24K)
      double* pooled = (double*)(qreg + 8192); // [8][ph2]  [24K,28K)
      const int P = (f >= 8) ? 8 : f;          // si0:8 si1:8 si2:4 si3:2
      const int lP = (f >= 8) ? 3 : ((f == 4) ? 2 : 1);
      const int items = 8 * ph2, work = items * P, dpp = f / P;
      if (tid < work) {
        int it = tid >> lP, part = tid & (P - 1);
        int cc = it >> (2 * si), rem = it & (ph2 - 1);
        int y = rem >> si, x = rem & (ph - 1);
        const double* basep = zres + cc * 256 + (y * f) * 16 + x * f;
        double s = 0.0;
        for (int dy = part * dpp; dy < part * dpp + dpp; dy++) {
          const double* rp = basep + dy * 16;
          #pragma unroll 4
          for (int dx = 0; dx < f; dx++) s += rp[dx];
        }
        pp[tid] = s;
      }
      __syncthreads();
      if (tid < items) {
        double s = 0.0;
        for (int p2 = 0; p2 < P; p2++) s += pp[(tid << lP) + p2];
        pooled[tid] = s / (double)(f * f);     // tid = cc*ph2+rem
      }
      __syncthreads();
      if (tid < items) {
        int rem = tid >> 3, cc = tid & 7;      // coalesced publish
        __hip_atomic_store(&rv64[(((b << 8) + rem) << 5) + co0 + cc],
                           pooled[cc * ph2 + rem],
                           __ATOMIC_RELAXED, __HIP_MEMORY_SCOPE_AGENT);
      }
    }
    groupbar(&flags[(b << 4) + si * 2]);

    // ---------- argmin: rows jq::4, all 4096 codes (R5 verbatim) ------------
    // 4 codes/thread, single pass; j-rows in two groups of 4 (16-reg acc,
    // proven no-spill). f32 scan + exact f32-top-2 + f64 rescore.
    {
      const int count = (ph2 > jq) ? ((ph2 - jq + 3) >> 2) : 0;
      float*  rvt32 = (float*)qreg;                          // [64][32] 8KB
      double* rvt64 = (double*)(qreg + 8192);                // [64][32] 16KB
      unsigned long long* wdu = (unsigned long long*)(qreg + 24576); // 2KB
      unsigned short* cand = (unsigned short*)(qreg + 26624);        // 256B
      for (int t = tid; t < 2048; t += TPB) {  // stage 64 rows (padded rows
        int m = t >> 5, k = t & 31;            // finite garbage, never output)
        double v = __hip_atomic_load(&rv64[(((b << 8) + jq + 4 * m) << 5) + k],
                                     __ATOMIC_RELAXED, __HIP_MEMORY_SCOPE_AGENT);
        rvt64[t] = v;
        rvt32[t] = (float)v;
      }
      __syncthreads();
      if (count) {
        const int e0 = tid << 2;               // 4 consecutive codes
        const f32x4 es4 = *(const f32x4*)(emb_sq32 + e0);
        const int lane = tid & 63, wv_ = tid >> 6;
        for (int m0 = 0; m0 < count; m0 += 8) {
          #pragma unroll
          for (int jg = 0; jg < 2; jg++) {
            f32x4 acc[4];
            #pragma unroll
            for (int j = 0; j < 4; j++) acc[j] = (f32x4){0.f, 0.f, 0.f, 0.f};
            const f32x4* __restrict__ eb = (const f32x4*)emb_ti + (tid << 1);
            #pragma unroll 4
            for (int k2 = 0; k2 < 16; k2++) {
              f32x4 E0 = eb[k2 * 2048];        // codes e0..e0+1, k pair
              f32x4 E1 = eb[k2 * 2048 + 1];    // codes e0+2..e0+3
              #pragma unroll
              for (int j = 0; j < 4; j++) {
                f32x2 r2 = *(const f32x2*)(rvt32 + ((m0 + jg * 4 + j) << 5)
                                           + (k2 << 1));
                f32x2 lo = {acc[j].x, acc[j].y}, hi = {acc[j].z, acc[j].w};
                lo = pkfma((f32x2){r2.x, r2.x}, (f32x2){E0.x, E0.z}, lo);
                lo = pkfma((f32x2){r2.y, r2.y}, (f32x2){E0.y, E0.w}, lo);
                hi = pkfma((f32x2){r2.x, r2.x}, (f32x2){E1.x, E1.z}, hi);
                hi = pkfma((f32x2){r2.y, r2.y}, (f32x2){E1.y, E1.w}, hi);
                acc[j] = (f32x4){lo.x, lo.y, hi.x, hi.y};
              }
            }
            #pragma unroll
            for (int j = 0; j < 4; j++) {      // exact top-2, ascending codes
              float d0 = es4.x - 2.f * acc[j].x;
              float d1 = es4.y - 2.f * acc[j].y;
              float d2 = es4.z - 2.f * acc[j].z;
              float d3 = es4.w - 2.f * acc[j].w;
              float b1 = d0, b2; int i1 = e0, i2;
              if (d1 < b1) { b2 = b1; i2 = i1; b1 = d1; i1 = e0 + 1; }
              else         { b2 = d1; i2 = e0 + 1; }
              if (d2 < b1) { b2 = b1; i2 = i1; b1 = d2; i1 = e0 + 2; }
              else if (d2 < b2) { b2 = d2; i2 = e0 + 2; }
              if (d3 < b1) { b2 = b1; i2 = i1; b1 = d3; i1 = e0 + 3; }
              else if (d3 < b2) { b2 = d3; i2 = e0 + 3; }
              unsigned long long p1 =
                  ((unsigned long long)monokey(b1) << 32) | (unsigned)i1;
              unsigned long long p2 =
                  ((unsigned long long)monokey(b2) << 32) | (unsigned)i2;
              #pragma unroll
              for (int off = 32; off >= 1; off >>= 1) {  // top-2 butterfly
                unsigned long long q1 = __shfl_xor(p1, off, 64);
                unsigned long long q2 = __shfl_xor(p2, off, 64);
                unsigned long long lo = p1 < q1 ? p1 : q1;
                unsigned long long hi = p1 < q1 ? q1 : p1;
                unsigned long long m2 = p2 < q2 ? p2 : q2;
                p1 = lo;
                p2 = hi < m2 ? hi : m2;
              }
              if (lane == 0) {
                int row = (jg << 2) + j;
                wdu[(wv_ << 4) + (row << 1)]     = p1;
                wdu[(wv_ << 4) + (row << 1) + 1] = p2;
              }
            }
          }
          __syncthreads();
          if (tid < 8 && m0 + tid < count) {   // cross-wave top-2 merge
            unsigned long long G1 = ~0ull, G2 = ~0ull;
            #pragma unroll
            for (int w = 0; w < 16; w++) {
              unsigned long long a1 = wdu[(w << 4) + (tid << 1)];
              unsigned long long a2 = wdu[(w << 4) + (tid << 1) + 1];
              if (a1 < G1) { G2 = (G1 < a2 ? G1 : a2); G1 = a1; }
              else if (a1 < G2) G2 = a1;
            }
            cand[((m0 + tid) << 1)]     = (unsigned short)(G1 & 0xFFFFu);
            cand[((m0 + tid) << 1) + 1] = (unsigned short)(G2 & 0xFFFFu);
          }
          __syncthreads();                     // wdu reused next chunk
        }
        // f64 rescore of the exact f32-top-2 -> final winner
        if (tid < 2 * count) {
          int m = tid >> 1, cs = tid & 1;
          int c = cand[(m << 1) + cs];
          const float* er = emb + (c << 5);
          double dot = 0.0;
          #pragma unroll
          for (int k = 0; k < 32; k++)
            dot = fma(rvt64[(m << 5) + k], (double)er[k], dot);
          double d = emb_sq[c] - 2.0 * dot;
          double doth = __shfl_xor(d, 1, 64);
          int coth = __shfl_xor(c, 1, 64);
          if (cs == 0) {
            int wc = (doth < d || (doth == d && coth < c)) ? coth : c;
            int n = jq + (m << 2);
            __hip_atomic_store(&win[(b << 8) + n], wc,
                               __ATOMIC_RELAXED, __HIP_MEMORY_SCOPE_AGENT);
            out_idx[b * IDXW + idx_off + n] = (float)wc;
          }
        }
      }
    }
    groupbar(&flags[(b << 4) + si * 2 + 1]);

    // ---------- gather winners (fidx @64320, outside simg halo) -------------
    unsigned short* fidx = (unsigned short*)(base + 64320);
    if (tid < ph2)
      fidx[tid] = (unsigned short)__hip_atomic_load(&win[(b << 8) + tid],
                      __ATOMIC_RELAXED, __HIP_MEMORY_SCOPE_AGENT);
    __syncthreads();

    // ---------- upsample (f32) into halo image simg[32][18][18] -------------
    float* simg = (float*)(base + 16384);
    for (int i = tid; i < 32 * 324; i += TPB) simg[i] = 0.f;  // zero + halo
    float* wtab = (float*)(base + 64000);
    int*   itab = (int*)(base + 64256);
    if (si < 4 && tid < 64) {
      double scale = (double)ph / 16.0;
      int oy = tid >> 2, kk = tid & 3;
      double src = ((double)oy + 0.5) * scale - 0.5;
      double fi = floor(src);
      if (kk == 0) itab[oy] = (int)fi;
      wtab[tid] = (float)cubicw(src - fi - (double)(kk - 1));
    }
    __syncthreads();
    if (si == 4) {
      #pragma unroll
      for (int t = 0; t < 2; t++) {            // f32x4 gather: 4 ch per item
        int i = t * TPB + tid;                 // i < 2048 = 256 pix x 8 groups
        int pix = i & 255, g = i >> 8;
        f32x4 v = *(const f32x4*)(emb + (int)fidx[pix] * NC + g * 4);
        int hb = (1 + (pix >> 4)) * 18 + 1 + (pix & 15);
        simg[(g * 4 + 0) * 324 + hb] = v.x;
        simg[(g * 4 + 1) * 324 + hb] = v.y;
        simg[(g * 4 + 2) * 324 + hb] = v.z;
        simg[(g * 4 + 3) * 324 + hb] = v.w;
      }
    } else {
      const int CH = (si <= 1) ? 32 : ((si == 2) ? 16 : 8);
      const int nhalf = 32 / CH;
      float* tt = (float*)(base + 57856);      // [CH][16][ph] <= 4KB
      float* qs = (float*)(base + 61952);      // [CH][ph2]    <= 2KB
      for (int half = 0; half < nhalf; half++) {
        int c0 = half * CH;
        for (int i = tid; i < CH * ph2; i += TPB) {
          int cc = i >> (2 * si), rem = i & (ph2 - 1);
          qs[i] = emb[(int)fidx[rem] * NC + c0 + cc];
        }
        __syncthreads();
        for (int i = tid; i < CH * 16 * ph; i += TPB) {   // H pass (y)
          int x = i & (ph - 1), oy = (i >> si) & 15, cc = i >> (4 + si);
          int i0 = itab[oy];
          float s = 0.f;
          #pragma unroll
          for (int k = 0; k < 4; k++) {
            int iy = min(max(i0 + k - 1, 0), ph - 1);
            s = fmaf(wtab[oy * 4 + k], qs[(cc * ph + iy) * ph + x], s);
          }
          tt[i] = s;
        }
        __syncthreads();
        for (int i = tid; i < CH * 256; i += TPB) {       // W pass (x)
          int ox = i & 15, oy = (i >> 4) & 15, cc = i >> 8;
          int i0 = itab[ox];
          float s = 0.f;
          #pragma unroll
          for (int k = 0; k < 4; k++) {
            int ix = min(max(i0 + k - 1, 0), ph - 1);
            s = fmaf(wtab[ox * 4 + k], tt[(cc * 16 + oy) * ph + ix], s);
          }
          simg[(c0 + cc) * 324 + (1 + oy) * 18 + 1 + ox] = s;
        }
        __syncthreads();                       // tt/qs reused next half
      }
    }
    __syncthreads();

    // ---------- phi: 0.5*x + 0.5*(conv3x3(x)+b); halo reads, no selects -----
    {
      int pix = tid & 255, sub = tid >> 8;     // 4 subs x 2 co = 8 co
      int x = pix & 15, y = pix >> 4;
      float a0 = 0.f, a1 = 0.f;
      // weights straight from global: wave-uniform address -> L2 broadcast
      const float* wp0 = phi_w + ((pis[si] * NC + co0 + sub * 2) * NC) * 9;
      const float* wp1 = wp0 + NC * 9;
      for (int ci = 0; ci < NC; ci++) {
        const float* sb = simg + ci * 324 + y * 18 + x;   // halo coords
        float wv[9];
        #pragma unroll
        for (int ky = 0; ky < 3; ky++)
          #pragma unroll
          for (int kx = 0; kx < 3; kx++)
            wv[ky * 3 + kx] = sb[ky * 18 + kx];
        #pragma unroll
        for (int k = 0; k < 9; k++) a0 = fmaf(wv[k], wp0[ci * 9 + k], a0);
        #pragma unroll
        for (int k = 0; k < 9; k++) a1 = fmaf(wv[k], wp1[ci * 9 + k], a1);
      }
      double lsum = 0.0;
      #pragma unroll
      for (int jj = 0; jj < 2; jj++) {
        int col = (sub << 1) + jj;
        float aj = jj ? a1 : a0;
        float val = simg[(co0 + col) * 324 + (1 + y) * 18 + 1 + x] * 0.5f
                  + (aj + phi_b[pis[si] * NC + co0 + col]) * 0.5f;
        int li = (col << 8) + pix;
        double zr = zres[li] - (double)val;
        zres[li] = zr;
        if (si == 4) {
          int gi = ((b * NC + co0 + col) << 8) + pix;
          out_zhat[gi] = (float)((double)z[gi] - zr);
        }
        lsum += zr * zr;                       // z_hat - z == -z_res
      }
      __syncthreads();                         // simg consumed
      #pragma unroll
      for (int off = 32; off >= 1; off >>= 1)
        lsum += __shfl_xor(lsum, off, 64);
      double* red = (double*)(base + 64832);
      if ((tid & 63) == 0) red[tid >> 6] = lsum;
      __syncthreads();
      if (tid < 16) {
        double v = red[tid];
        #pragma unroll
        for (int off = 8; off >= 1; off >>= 1) v += __shfl_xor(v, off, 16);
        if (tid == 0) bloss += v;
      }
      __syncthreads();
    }
  }

  // ---------- global loss: one f64 atomic per block; last arriver writes ----
  if (tid == 0) {
    double old = unsafeAtomicAdd(loss_d, bloss); (void)old;
    asm volatile("s_waitcnt vmcnt(0)" ::: "memory");
    unsigned n = __hip_atomic_fetch_add(cnt, 1u, __ATOMIC_RELAXED,
                                        __HIP_MEMORY_SCOPE_AGENT);
    if (n == GRID - 1u) {
      double tot = __hip_atomic_load(loss_d, __ATOMIC_RELAXED,
                                     __HIP_MEMORY_SCOPE_AGENT);
      *out_loss = (float)(tot * (1.25 / (5.0 * (double)NTOT)));
    }
  }
}

extern "C" void kernel_launch(void* const* d_in, const int* in_sizes, int n_in,
                              void* d_out, int out_size, void* d_ws, size_t ws_size,
                              hipStream_t stream) {
  const float* z     = (const float*)d_in[0];   // [64,32,16,16]
  const float* emb   = (const float*)d_in[1];   // [4096,32]
  const float* phi_w = (const float*)d_in[2];   // [4,32,32,3,3]
  const float* phi_b = (const float*)d_in[3];   // [4,32]

  float* out      = (float*)d_out;
  float* out_zhat = out;
  float* out_loss = out + NTOT;
  float* out_idx  = out + NTOT + 1;             // [64,341] as floats

  double* ws       = (double*)d_ws;
  double* rv64     = ws;                            // 64*256*32 f64 = 4 MB
  double* emb_sq   = rv64 + 64 * 256 * NC;          // 4096 f64
  double* loss_d   = emb_sq + NE;                   // 1 f64 (+1 pad for 16B)
  float*  emb_ti   = (float*)(loss_d + 2);          // 131072 f32 (16B aligned)
  float*  emb_sq32 = emb_ti + NE * NC;              // 4096 f32
  int*    win      = (int*)(emb_sq32 + NE);         // 64*256 int
  unsigned* cnt    = (unsigned*)(win + NB * 256);   // 1
  unsigned* gbar   = cnt + 1;                       // 1
  unsigned* flags  = gbar + 1;                      // 64*16 one-shot cells

  k_fused<<<GRID, TPB, 0, stream>>>(z, emb, phi_w, phi_b,
                                    rv64, emb_sq, loss_d, emb_ti, emb_sq32,
                                    win, cnt, gbar, flags,
                                    out_zhat, out_loss, out_idx);
}

// Round 13
// 434.317 us; speedup vs baseline: 4.0231x; 4.0231x over previous
//
#include <hip/hip_runtime.h>

#define NB 64
#define NC 32
#define NH 16
#define NW 16
#define NE 4096
#define NTOT (NB*NC*NH*NW)   // 524288
#define IDXW 341             // 1+4+16+64+256
#define GRID 256
#define TPB 1024

typedef float f32x2 __attribute__((ext_vector_type(2)));
typedef float f32x4 __attribute__((ext_vector_type(4)));

__device__ __forceinline__ f32x2 pkfma(f32x2 a, f32x2 b, f32x2 c) {
#if __has_builtin(__builtin_elementwise_fma)
  return __builtin_elementwise_fma(a, b, c);
#else
  return (f32x2){fmaf(a.x, b.x, c.x), fmaf(a.y, b.y, c.y)};
#endif
}

__device__ __forceinline__ double cubicw(double x) {
  const double A = -0.75;
  x = fabs(x);
  if (x <= 1.0) return ((A + 2.0) * x - (A + 3.0)) * x * x + 1.0;
  if (x < 2.0)  return A * (((x - 5.0) * x + 8.0) * x - 4.0);
  return 0.0;
}

// monotonic u32 key: smaller float <=> smaller key (handles negatives)
__device__ __forceinline__ unsigned monokey(float f) {
  unsigned u = __float_as_uint(f);
  return (u & 0x80000000u) ? ~u : (u | 0x80000000u);
}

__device__ __forceinline__ unsigned aload(unsigned* p) {
  return __hip_atomic_load(p, __ATOMIC_RELAXED, __HIP_MEMORY_SCOPE_AGENT);
}

// 4-party group barrier, fence-free (proven R2-R11): sc0sc1 publishes are
// coherent at IF$; __syncthreads drains vmcnt before arrive.
__device__ __forceinline__ void groupbar(unsigned* fl) {
  __syncthreads();
  if (threadIdx.x == 0) {
    __hip_atomic_fetch_add(fl, 1u, __ATOMIC_RELAXED, __HIP_MEMORY_SCOPE_AGENT);
    while (aload(fl) < 4u) __builtin_amdgcn_s_sleep(1);
  }
  __syncthreads();
}

// R5 kernel (435 us, clean counters) + fault-path hardening. R12 (byte-
// identical to R5) aborted once: the only OOB-capable path is an emb gather
// through a poisoned (0xAAAA -> 43690) win/cand value if a barrier anomaly
// ever reorders gather before the scan writes. All emb indices derived from
// fidx/cand are now masked & 4095 (a few v_and in cold loops): a racing
// iteration becomes a wrong value (absmax-visible) instead of a GPU fault;
// a healthy run is bit-identical to R5.
// Ledger of failed departures: R6 crash (LDS alias), R7/R8/R11 phi spill
// (halo conv + global-weight streaming blows the 64-VGPR wall -> 3.9 GB
// scratch traffic), R9 (+65 us), R10 (+262 us). Compiler pins 64 VGPR;
// every phase lives within it (scan acc = 16 regs, phi packed f32x2 with
// LDS-staged weights).
__global__ __launch_bounds__(TPB)
__attribute__((amdgpu_waves_per_eu(4, 4)))
void k_fused(
    const float* __restrict__ z, const float* __restrict__ emb,
    const float* __restrict__ phi_w, const float* __restrict__ phi_b,
    double* __restrict__ rv64, double* __restrict__ emb_sq,
    double* __restrict__ loss_d, float* __restrict__ emb_ti,
    float* __restrict__ emb_sq32, int* __restrict__ win,
    unsigned* __restrict__ cnt, unsigned* __restrict__ gbar,
    unsigned* __restrict__ flags,
    float* __restrict__ out_zhat, float* __restrict__ out_loss,
    float* __restrict__ out_idx)
{
  __shared__ double lds[8192];                 // 64 KB
  double* zres = lds;                          // [8][256] f64, persistent [0,16K)
  char* qreg   = (char*)lds + 16384;           // 32 KB multi-use [16K,48K)
  char* ttreg  = (char*)lds + 49152;           // 16 KB multi-use [48K,64K)

  const int tid = threadIdx.x;
  // group = {b, b+64, b+128, b+192}: all == b (mod 8) -> same XCD under the
  // default bid%8 XCD round-robin -> exchange stays XCD-local.
  const int b = blockIdx.x & 63, jq = blockIdx.x >> 6;
  const int co0 = jq * 8;

  // idempotent CAS-init of poisoned (0xAA) sync cells
  if (tid < 16) atomicCAS(&flags[(b << 4) + tid], 0xAAAAAAAAu, 0u);
  if (tid == 0) {
    atomicCAS((unsigned long long*)loss_d, 0xAAAAAAAAAAAAAAAAull, 0ull);
    atomicCAS(cnt, 0xAAAAAAAAu, 0u);
    atomicCAS(gbar, 0xAAAAAAAAu, 0u);
  }

  // ---------- setup: zres <- z slice; emb_ti (k-pair interleave) + emb_sq ---
  #pragma unroll
  for (int t = 0; t < 2; t++) {
    int i = t * TPB + tid;
    zres[i] = (double)z[((b * NC + co0) << 8) + i];
  }
  {
    int c0 = blockIdx.x * 16;                  // 16 codes per block
    if (tid < 512) {
      int cl = tid >> 5, k = tid & 31;
      // layout: emb_ti[k2*8192 + code*2 + (k&1)]
      emb_ti[(k >> 1) * 8192 + (c0 + cl) * 2 + (k & 1)] = emb[(c0 + cl) * NC + k];
    }
    if (tid < 16) {
      const float* er = emb + (c0 + tid) * NC;
      double s = 0.0;
      #pragma unroll
      for (int j = 0; j < 8; j++)
        s += (double)er[4*j]*er[4*j] + (double)er[4*j+1]*er[4*j+1]
           + (double)er[4*j+2]*er[4*j+2] + (double)er[4*j+3]*er[4*j+3];
      emb_sq[c0 + tid] = s;
      emb_sq32[c0 + tid] = (float)s;
    }
  }
  // one-time FENCED tree barrier (only threadfence pair in the kernel):
  // publishes emb_ti/emb_sq/emb_sq32 for normal L2-cached reads thereafter.
  __syncthreads();
  if (tid == 0) {
    __threadfence();                           // release (wb L2)
    __hip_atomic_fetch_add(&flags[(b << 4) + 15], 1u, __ATOMIC_RELAXED,
                           __HIP_MEMORY_SCOPE_AGENT);
    if (jq == 0) {
      while (aload(&flags[(b << 4) + 15]) < 4u) __builtin_amdgcn_s_sleep(1);
      __hip_atomic_fetch_add(gbar, 1u, __ATOMIC_RELAXED,
                             __HIP_MEMORY_SCOPE_AGENT);
      while (aload(gbar) < 64u) __builtin_amdgcn_s_sleep(4);
      __hip_atomic_store(&flags[(b << 4) + 14], 1u, __ATOMIC_RELAXED,
                         __HIP_MEMORY_SCOPE_AGENT);
    } else {
      while (aload(&flags[(b << 4) + 14]) < 1u) __builtin_amdgcn_s_sleep(1);
    }
    __threadfence();                           // acquire (inv L2)
  }
  __syncthreads();

  double bloss = 0.0;
  // ticks = np.linspace(1/12, 11/12, 4) f64: si=2 tie breaks to pi=2
  const int pis[5]  = {0, 1, 2, 2, 3};
  const int offs[5] = {0, 1, 5, 21, 85};

  for (int si = 0; si < 5; si++) {
    const int ph = 1 << si, f = NH / ph, ph2 = ph * ph;
    const int idx_off = offs[si];

    // ---------- pool own 8 channels (f64) -> publish rv64 [b][n][c] ---------
    if (si == 4) {
      #pragma unroll
      for (int t = 0; t < 2; t++) {
        int i = t * TPB + tid;
        int pix = i >> 3, cc = i & 7;          // coalesced publish
        __hip_atomic_store(&rv64[(((b << 8) + pix) << 5) + co0 + cc],
                           zres[cc * 256 + pix],
                           __ATOMIC_RELAXED, __HIP_MEMORY_SCOPE_AGENT);
      }
    } else {
      double* pp = (double*)qreg;              // [work] partials  [16K,24K)
      double* pooled = (double*)(qreg + 8192); // [8][ph2]         [24K,28K)
      const int P = (f >= 8) ? 8 : f;          // si0:8 si1:8 si2:4 si3:2
      const int lP = (f >= 8) ? 3 : ((f == 4) ? 2 : 1);
      const int items = 8 * ph2, work = items * P, dpp = f / P;
      if (tid < work) {
        int it = tid >> lP, part = tid & (P - 1);
        int cc = it >> (2 * si), rem = it & (ph2 - 1);
        int y = rem >> si, x = rem & (ph - 1);
        const double* basep = zres + cc * 256 + (y * f) * 16 + x * f;
        double s = 0.0;
        for (int dy = part * dpp; dy < part * dpp + dpp; dy++) {
          const double* rp = basep + dy * 16;
          #pragma unroll 4
          for (int dx = 0; dx < f; dx++) s += rp[dx];
        }
        pp[tid] = s;
      }
      __syncthreads();
      if (tid < items) {
        double s = 0.0;
        for (int p2 = 0; p2 < P; p2++) s += pp[(tid << lP) + p2];
        pooled[tid] = s / (double)(f * f);     // tid = cc*ph2+rem
      }
      __syncthreads();
      if (tid < items) {
        int rem = tid >> 3, cc = tid & 7;      // coalesced publish
        __hip_atomic_store(&rv64[(((b << 8) + rem) << 5) + co0 + cc],
                           pooled[cc * ph2 + rem],
                           __ATOMIC_RELAXED, __HIP_MEMORY_SCOPE_AGENT);
      }
    }
    groupbar(&flags[(b << 4) + si * 2]);

    // ---------- argmin: rows jq::4, all 4096 codes ---------------------------
    // 4 codes/thread, single pass; j-rows in two groups of 4 (peak liveness
    // ~60 VGPR, fits the 64-reg budget). f32 scan + exact-top-2 + f64
    // rescore.
    {
      const int count = (ph2 > jq) ? ((ph2 - jq + 3) >> 2) : 0;
      float*  rvt32 = (float*)qreg;                          // [64][32] 8KB
      double* rvt64 = (double*)(qreg + 8192);                // [64][32] 16KB
      unsigned long long* wdu = (unsigned long long*)(qreg + 24576); // [16][16]
      unsigned short* cand = (unsigned short*)(qreg + 26624);        // [128]
      for (int t = tid; t < 2048; t += TPB) {  // stage 64 rows (padded rows
        int m = t >> 5, k = t & 31;            // finite garbage, never output)
        double v = __hip_atomic_load(&rv64[(((b << 8) + jq + 4 * m) << 5) + k],
                                     __ATOMIC_RELAXED, __HIP_MEMORY_SCOPE_AGENT);
        rvt64[t] = v;
        rvt32[t] = (float)v;
      }
      __syncthreads();
      if (count) {
        const int e0 = tid << 2;               // 4 consecutive codes
        const f32x4 es4 = *(const f32x4*)(emb_sq32 + e0);
        const int lane = tid & 63, wv_ = tid >> 6;
        for (int m0 = 0; m0 < count; m0 += 8) {
          #pragma unroll
          for (int jg = 0; jg < 2; jg++) {
            f32x4 acc[4];
            #pragma unroll
            for (int j = 0; j < 4; j++) acc[j] = (f32x4){0.f, 0.f, 0.f, 0.f};
            const f32x4* __restrict__ eb = (const f32x4*)emb_ti + (tid << 1);
            #pragma unroll 4
            for (int k2 = 0; k2 < 16; k2++) {
              f32x4 E0 = eb[k2 * 2048];        // codes e0..e0+1, k pair
              f32x4 E1 = eb[k2 * 2048 + 1];    // codes e0+2..e0+3
              #pragma unroll
              for (int j = 0; j < 4; j++) {
                f32x2 r2 = *(const f32x2*)(rvt32 + ((m0 + jg * 4 + j) << 5)
                                           + (k2 << 1));
                f32x2 lo = {acc[j].x, acc[j].y}, hi = {acc[j].z, acc[j].w};
                lo = pkfma((f32x2){r2.x, r2.x}, (f32x2){E0.x, E0.z}, lo);
                lo = pkfma((f32x2){r2.y, r2.y}, (f32x2){E0.y, E0.w}, lo);
                hi = pkfma((f32x2){r2.x, r2.x}, (f32x2){E1.x, E1.z}, hi);
                hi = pkfma((f32x2){r2.y, r2.y}, (f32x2){E1.y, E1.w}, hi);
                acc[j] = (f32x4){lo.x, lo.y, hi.x, hi.y};
              }
            }
            #pragma unroll
            for (int j = 0; j < 4; j++) {      // exact top-2, ascending codes
              float d0 = es4.x - 2.f * acc[j].x;
              float d1 = es4.y - 2.f * acc[j].y;
              float d2 = es4.z - 2.f * acc[j].z;
              float d3 = es4.w - 2.f * acc[j].w;
              float b1 = d0, b2; int i1 = e0, i2;
              if (d1 < b1) { b2 = b1; i2 = i1; b1 = d1; i1 = e0 + 1; }
              else         { b2 = d1; i2 = e0 + 1; }
              if (d2 < b1) { b2 = b1; i2 = i1; b1 = d2; i1 = e0 + 2; }
              else if (d2 < b2) { b2 = d2; i2 = e0 + 2; }
              if (d3 < b1) { b2 = b1; i2 = i1; b1 = d3; i1 = e0 + 3; }
              else if (d3 < b2) { b2 = d3; i2 = e0 + 3; }
              unsigned long long p1 =
                  ((unsigned long long)monokey(b1) << 32) | (unsigned)i1;
              unsigned long long p2 =
                  ((unsigned long long)monokey(b2) << 32) | (unsigned)i2;
              #pragma unroll
              for (int off = 32; off >= 1; off >>= 1) {  // top-2 butterfly
                unsigned long long q1 = __shfl_xor(p1, off, 64);
                unsigned long long q2 = __shfl_xor(p2, off, 64);
                unsigned long long lo = p1 < q1 ? p1 : q1;
                unsigned long long hi = p1 < q1 ? q1 : p1;
                unsigned long long m2 = p2 < q2 ? p2 : q2;
                p1 = lo;
                p2 = hi < m2 ? hi : m2;
              }
              if (lane == 0) {
                int row = (jg << 2) + j;
                wdu[(wv_ << 4) + (row << 1)]     = p1;
                wdu[(wv_ << 4) + (row << 1) + 1] = p2;
              }
            }
          }
          __syncthreads();
          if (tid < 8 && m0 + tid < count) {   // cross-wave top-2 merge
            unsigned long long G1 = ~0ull, G2 = ~0ull;
            #pragma unroll
            for (int w = 0; w < 16; w++) {
              unsigned long long a1 = wdu[(w << 4) + (tid << 1)];
              unsigned long long a2 = wdu[(w << 4) + (tid << 1) + 1];
              if (a1 < G1) { G2 = (G1 < a2 ? G1 : a2); G1 = a1; }
              else if (a1 < G2) G2 = a1;
            }
            cand[((m0 + tid) << 1)]     = (unsigned short)(G1 & 0xFFFFu);
            cand[((m0 + tid) << 1) + 1] = (unsigned short)(G2 & 0xFFFFu);
          }
          __syncthreads();                     // wdu reused next chunk
        }
        // f64 rescore of the exact f32-top-2 -> final winner
        if (tid < 2 * count) {
          int m = tid >> 1, cs = tid & 1;
          int c = (int)cand[(m << 1) + cs] & (NE - 1);   // hardened index
          const float* er = emb + (c << 5);
          double dot = 0.0;
          #pragma unroll
          for (int k = 0; k < 32; k++)
            dot = fma(rvt64[(m << 5) + k], (double)er[k], dot);
          double d = emb_sq[c] - 2.0 * dot;
          double doth = __shfl_xor(d, 1, 64);
          int coth = __shfl_xor(c, 1, 64);
          if (cs == 0) {
            int wc = (doth < d || (doth == d && coth < c)) ? coth : c;
            int n = jq + (m << 2);
            __hip_atomic_store(&win[(b << 8) + n], wc,
                               __ATOMIC_RELAXED, __HIP_MEMORY_SCOPE_AGENT);
            out_idx[b * IDXW + idx_off + n] = (float)wc;
          }
        }
      }
    }
    groupbar(&flags[(b << 4) + si * 2 + 1]);

    // ---------- gather winners ----------
    unsigned short* fidx = (unsigned short*)(ttreg + 12800);   // [256]
    if (tid < ph2)
      fidx[tid] = (unsigned short)__hip_atomic_load(&win[(b << 8) + tid],
                      __ATOMIC_RELAXED, __HIP_MEMORY_SCOPE_AGENT);
    __syncthreads();

    // ---------- upsample (f32): full 32-ch q in LDS (redundant x4) ----------
    float* simg = (float*)qreg;                // [32][256] f32, 32KB
    if (si == 4) {
      for (int i = tid; i < 32 * 256; i += TPB)
        simg[i] = emb[((int)fidx[i & 255] & (NE - 1)) * NC + (i >> 8)];
    } else {
      float* wtab = (float*)(ttreg + 12288);   // [16][4] f32
      int* itab = (int*)(ttreg + 12544);       // [16]
      double scale = (double)ph / 16.0;
      if (tid < 64) {
        int oy = tid >> 2, kk = tid & 3;
        double src = ((double)oy + 0.5) * scale - 0.5;
        double fi = floor(src);
        if (kk == 0) itab[oy] = (int)fi;
        wtab[tid] = (float)cubicw(src - fi - (double)(kk - 1));
      }
      __syncthreads();
      int CH = (si == 3) ? 16 : 32, nhalf = (si == 3) ? 2 : 1;
      float* qs = (float*)(ttreg + 8192);      // <=4KB gather buf
      float* tt = (float*)ttreg;               // <=8KB H-pass intermediate
      for (int half = 0; half < nhalf; half++) {
        int c0 = half * CH;
        for (int i = tid; i < CH * ph2; i += TPB) {
          int cc = i >> (2 * si), rem = i & (ph2 - 1);
          qs[i] = emb[((int)fidx[rem] & (NE - 1)) * NC + c0 + cc];
        }
        __syncthreads();
        for (int i = tid; i < CH * 16 * ph; i += TPB) {   // H pass (y)
          int x = i & (ph - 1), oy = (i >> si) & 15, cc = i >> (4 + si);
          int i0 = itab[oy];
          float s = 0.f;
          #pragma unroll
          for (int k = 0; k < 4; k++) {
            int iy = min(max(i0 + k - 1, 0), ph - 1);
            s = fmaf(wtab[oy * 4 + k], qs[(cc * ph + iy) * ph + x], s);
          }
          tt[i] = s;
        }
        __syncthreads();
        for (int i = tid; i < CH * 256; i += TPB) {       // W pass (x)
          int ox = i & 15, oy = (i >> 4) & 15, cc = i >> 8;
          int i0 = itab[ox];
          float s = 0.f;
          #pragma unroll
          for (int k = 0; k < 4; k++) {
            int ix = min(max(i0 + k - 1, 0), ph - 1);
            s = fmaf(wtab[ox * 4 + k], tt[(cc * 16 + oy) * ph + ix], s);
          }
          simg[(c0 + cc) * 256 + oy * 16 + ox] = s;
        }
        __syncthreads();
      }
    }
    __syncthreads();

    // ---------- phi (packed f32): 0.5*x + 0.5*(conv3x3(x)+b); zres f64 ------
    {
      float* lw2 = (float*)ttreg;              // co-pair interleaved, 9216B
      const float* wsrc = phi_w + (pis[si] * NC + co0) * NC * 9;
      for (int i = tid; i < 2304; i += TPB) {
        int co = i / 288, rem = i - co * 288;  // rem = ci*9+k
        lw2[(((co >> 1) * 288 + rem) << 1) + (co & 1)] = wsrc[i];
      }
      __syncthreads();
      int pix = tid & 255, sub = tid >> 8;     // 4 subs x 2 co = 8 co
      int x = pix & 15, y = pix >> 4;
      f32x2 a = {0.f, 0.f};
      const f32x2* wp = (const f32x2*)lw2 + sub * 288;
      for (int ci = 0; ci < NC; ci++) {
        float wv[9];
        #pragma unroll
        for (int ky = 0; ky < 3; ky++) {
          int yy = y + ky - 1;
          #pragma unroll
          for (int kx = 0; kx < 3; kx++) {
            int xx = x + kx - 1;
            wv[ky * 3 + kx] = (yy >= 0 && yy < NH && xx >= 0 && xx < NW)
                              ? simg[(ci << 8) + yy * 16 + xx] : 0.f;
          }
        }
        #pragma unroll
        for (int k = 0; k < 9; k++)
          a = pkfma((f32x2){wv[k], wv[k]}, wp[ci * 9 + k], a);
      }
      double lsum = 0.0;
      #pragma unroll
      for (int jj = 0; jj < 2; jj++) {
        int col = (sub << 1) + jj;
        float aj = jj ? a.y : a.x;
        float val = simg[((co0 + col) << 8) + pix] * 0.5f
                  + (aj + phi_b[pis[si] * NC + co0 + col]) * 0.5f;
        int li = (col << 8) + pix;
        double zr = zres[li] - (double)val;
        zres[li] = zr;
        if (si == 4) {
          int gi = ((b * NC + co0 + col) << 8) + pix;
          out_zhat[gi] = (float)((double)z[gi] - zr);
        }
        lsum += zr * zr;                       // z_hat - z == -z_res
      }
      __syncthreads();                         // simg consumed
      // shuffle-based loss reduction (2 syncthreads instead of 10)
      #pragma unroll
      for (int off = 32; off >= 1; off >>= 1)
        lsum += __shfl_xor(lsum, off, 64);
      double* red = (double*)qreg;
      if ((tid & 63) == 0) red[tid >> 6] = lsum;
      __syncthreads();
      if (tid < 16) {
        double v = red[tid];
        #pragma unroll
        for (int off = 8; off >= 1; off >>= 1) v += __shfl_xor(v, off, 16);
        if (tid == 0) bloss += v;
      }
      __syncthreads();
    }
  }

  // ---------- global loss: one f64 atomic per block; last arriver writes ----
  if (tid == 0) {
    double old = unsafeAtomicAdd(loss_d, bloss); (void)old;
    asm volatile("s_waitcnt vmcnt(0)" ::: "memory");
    unsigned n = __hip_atomic_fetch_add(cnt, 1u, __ATOMIC_RELAXED,
                                        __HIP_MEMORY_SCOPE_AGENT);
    if (n == GRID - 1u) {
      double tot = __hip_atomic_load(loss_d, __ATOMIC_RELAXED,
                                     __HIP_MEMORY_SCOPE_AGENT);
      *out_loss = (float)(tot * (1.25 / (5.0 * (double)NTOT)));
    }
  }
}

extern "C" void kernel_launch(void* const* d_in, const int* in_sizes, int n_in,
                              void* d_out, int out_size, void* d_ws, size_t ws_size,
                              hipStream_t stream) {
  const float* z     = (const float*)d_in[0];   // [64,32,16,16]
  const float* emb   = (const float*)d_in[1];   // [4096,32]
  const float* phi_w = (const float*)d_in[2];   // [4,32,32,3,3]
  const float* phi_b = (const float*)d_in[3];   // [4,32]

  float* out      = (float*)d_out;
  float* out_zhat = out;
  float* out_loss = out + NTOT;
  float* out_idx  = out + NTOT + 1;             // [64,341] as floats

  double* ws       = (double*)d_ws;
  double* rv64     = ws;                            // 64*256*32 f64 = 4 MB
  double* emb_sq   = rv64 + 64 * 256 * NC;          // 4096 f64
  double* loss_d   = emb_sq + NE;                   // 1 f64 (+1 pad for 16B)
  float*  emb_ti   = (float*)(loss_d + 2);          // 131072 f32 (16B aligned)
  float*  emb_sq32 = emb_ti + NE * NC;              // 4096 f32
  int*    win      = (int*)(emb_sq32 + NE);         // 64*256 int
  unsigned* cnt    = (unsigned*)(win + NB * 256);   // 1
  unsigned* gbar   = cnt + 1;                       // 1
  unsigned* flags  = gbar + 1;                      // 64*16 one-shot cells

  k_fused<<<GRID, TPB, 0, stream>>>(z, emb, phi_w, phi_b,
                                    rv64, emb_sq, loss_d, emb_ti, emb_sq32,
                                    win, cnt, gbar, flags,
                                    out_zhat, out_loss, out_idx);
}